// Round 10
// baseline (127.096 us; speedup 1.0000x reference)
//
#include <hip/hip_runtime.h>
#include <hip/hip_bf16.h>
#include <math.h>

// HyperbolicMLR: out[b,c] = -asinh( 2*sc_diff_a / ((1+diff_norm2)*|a_c|) )
// R10: register-level software pipeline. Ring-4 LDS (BK=32 tiles), 1 barrier +
// 1 counted vmcnt(4) gate per tile. Fragment sets double-buffered (ping-pong):
// tile T prefetches T+1's bv/avA between its two MFMA half-bursts; tile-local
// avB reads drain under ph1. NO lgkm asm / NO sched_barrier in the body --
// the compiler emits fine-grained counted lgkm waits (m97 evidence), which is
// exactly the pipelining my earlier explicit pins defeated.

#define EPSF 1e-15f
#define MAXN 0.99999f   // (1 - 1e-5) / sqrt(c), c = 1

constexpr int Bdim = 4096;
constexpr int Ddim = 1024;
constexpr int Cdim = 4096;

typedef __bf16 bf16x8 __attribute__((ext_vector_type(8)));
typedef float  f32x4  __attribute__((ext_vector_type(4)));
typedef unsigned short u16;

__device__ __forceinline__ u16 f2bf(float f) {
  __hip_bfloat16 h = __float2bfloat16(f);   // RNE
  return *reinterpret_cast<const u16*>(&h);
}

__device__ __forceinline__ void gl_lds16(const u16* g, u16* l) {
  __builtin_amdgcn_global_load_lds(
      (const __attribute__((address_space(1))) void*)g,
      (__attribute__((address_space(3))) void*)l, 16, 0, 0);
}

// ---------------- prep kernels (unchanged, proven) ----------------

__global__ __launch_bounds__(256) void prep_x(const float* __restrict__ x,
                                              u16* __restrict__ xb,
                                              float* __restrict__ x2o) {
  const int b = blockIdx.x, t = threadIdx.x;
  float4 v = ((const float4*)(x + (size_t)b * Ddim))[t];
  float s = v.x * v.x + v.y * v.y + v.z * v.z + v.w * v.w;
  __shared__ float red[4];
#pragma unroll
  for (int o = 32; o > 0; o >>= 1) s += __shfl_down(s, o);
  if ((t & 63) == 0) red[t >> 6] = s;
  __syncthreads();
  s = red[0] + red[1] + red[2] + red[3];
  float norm  = sqrtf(s);
  float xn    = fmaxf(norm, EPSF);
  float scale = (xn > MAXN) ? (MAXN / xn) : 1.0f;
  if (t == 0) x2o[b] = s * scale * scale;
  ushort4 o4;
  o4.x = f2bf(v.x * scale); o4.y = f2bf(v.y * scale);
  o4.z = f2bf(v.z * scale); o4.w = f2bf(v.w * scale);
  ((ushort4*)(xb + (size_t)b * Ddim))[t] = o4;
}

// P row c -> PA row ((c>>4)<<5)+(c&15); A row c -> +16 (16-row interleave).
__global__ __launch_bounds__(256) void prep_pa(const float* __restrict__ a,
                                               const float* __restrict__ p,
                                               u16* __restrict__ pab,
                                               float* __restrict__ p2o,
                                               float* __restrict__ pao,
                                               float* __restrict__ ano) {
  const int c = blockIdx.x, t = threadIdx.x;
  float4 av = ((const float4*)(a + (size_t)c * Ddim))[t];
  float4 pv = ((const float4*)(p + (size_t)c * Ddim))[t];
  float sp2 = pv.x * pv.x + pv.y * pv.y + pv.z * pv.z + pv.w * pv.w;
  float spa = pv.x * av.x + pv.y * av.y + pv.z * av.z + pv.w * av.w;
  float sa2 = av.x * av.x + av.y * av.y + av.z * av.z + av.w * av.w;
  __shared__ float red[12];
#pragma unroll
  for (int o = 32; o > 0; o >>= 1) {
    sp2 += __shfl_down(sp2, o);
    spa += __shfl_down(spa, o);
    sa2 += __shfl_down(sa2, o);
  }
  if ((t & 63) == 0) { int w = t >> 6; red[w] = sp2; red[4 + w] = spa; red[8 + w] = sa2; }
  __syncthreads();
  if (t == 0) {
    p2o[c] = red[0] + red[1] + red[2] + red[3];
    pao[c] = red[4] + red[5] + red[6] + red[7];
    ano[c] = sqrtf(red[8] + red[9] + red[10] + red[11]);
  }
  const int prP = ((c >> 4) << 5) + (c & 15);
  ushort4 oa, op;
  oa.x = f2bf(av.x); oa.y = f2bf(av.y); oa.z = f2bf(av.z); oa.w = f2bf(av.w);
  op.x = f2bf(pv.x); op.y = f2bf(pv.y); op.z = f2bf(pv.z); op.w = f2bf(pv.w);
  ((ushort4*)(pab + (size_t)prP * Ddim))[t]        = op;
  ((ushort4*)(pab + (size_t)(prP + 16) * Ddim))[t] = oa;
}

// ---------------- fused GEMM + epilogue ----------------

#define GATEV8() asm volatile("s_waitcnt vmcnt(8)" ::: "memory")
#define GATEV4() asm volatile("s_waitcnt vmcnt(4)" ::: "memory")
#define GATEV0() asm volatile("s_waitcnt vmcnt(0)" ::: "memory")
#define GATENONE()

struct Frag { bf16x8 bv[4]; bf16x8 av[4]; };

__global__ __launch_bounds__(512, 2) void gemm_ep(
    const u16* __restrict__ xb, const u16* __restrict__ pab,
    const float* __restrict__ x2g, const float* __restrict__ p2g,
    const float* __restrict__ pag, const float* __restrict__ ang,
    float* __restrict__ out) {
  // ring of 4 BK=32 K-tiles: 256 rows x 32 u16 (64-B rows), X and PA
  __shared__ u16 Xs[4][8192];      // 64 KiB
  __shared__ u16 PAs[4][8192];     // 64 KiB

  const int t = threadIdx.x;       // 0..511

  // XCD-aware bijective swizzle: 512 blocks = 8 chunks x 64
  const int flat  = blockIdx.y * 32 + blockIdx.x;
  const int swz   = (flat & 7) * 64 + (flat >> 3);
  const int chunk = swz >> 6;
  const int local = swz & 63;
  const int bx = chunk * 4 + (local & 3);     // 0..31  PA col-group
  const int by = local >> 2;                  // 0..15  X row-group

  const int lane = t & 63;
  const int wid  = t >> 6;       // 0..7
  const int wr   = wid >> 2;     // 0..1  (row half: 128 rows)
  const int wc   = wid & 3;      // 0..3  (PA quarter: 64 rows)

  // staging: thread t covers (r0 = t>>2, slot = t&3); source k-chunk
  // pre-swizzled (XOR involution, rule 21 both-sides).
  const int r0  = t >> 2;                              // 0..127
  const int sw8 = ((t & 3) ^ ((r0 >> 1) & 3)) * 8;     // u16
  const u16* xsrc  = xb  + (size_t)(by * 256 + r0) * Ddim + sw8;
  const u16* pasrc = pab + (size_t)(bx * 256 + r0) * Ddim + sw8;
  const int t8 = t * 8;
  const size_t half = (size_t)128 * Ddim;

  // fragment read offsets (per-tile buffer, u16 units)
  const int arow = wr * 128 + (lane & 15);
  const int brow = wc * 64  + (lane & 15);
  const int aoff = arow * 32 + (((lane >> 4) ^ ((arow >> 1) & 3)) * 8);
  const int boff = brow * 32 + (((lane >> 4) ^ ((brow >> 1) & 3)) * 8);

  f32x4 acc[8][4];
  const f32x4 zero = {0.f, 0.f, 0.f, 0.f};
#pragma unroll
  for (int m = 0; m < 8; ++m)
#pragma unroll
    for (int n = 0; n < 4; ++n) acc[m][n] = zero;

  Frag fsA, fsB;

#define PREFETCH(FS, BI) do {                                         \
    const u16* Xn  = &Xs[(BI)][0];                                    \
    const u16* PAn = &PAs[(BI)][0];                                   \
    _Pragma("unroll")                                                 \
    for (int i = 0; i < 4; ++i)                                       \
      FS.bv[i] = *(const bf16x8*)&PAn[boff + i * 512];                \
    _Pragma("unroll")                                                 \
    for (int i = 0; i < 4; ++i)                                       \
      FS.av[i] = *(const bf16x8*)&Xn[aoff + i * 512];                 \
  } while (0)

#define MROW4(M, AV, FS) do {                                         \
    acc[M][0] = __builtin_amdgcn_mfma_f32_16x16x32_bf16(AV, FS.bv[0], acc[M][0], 0, 0, 0); \
    acc[M][1] = __builtin_amdgcn_mfma_f32_16x16x32_bf16(AV, FS.bv[1], acc[M][1], 0, 0, 0); \
    acc[M][2] = __builtin_amdgcn_mfma_f32_16x16x32_bf16(AV, FS.bv[2], acc[M][2], 0, 0, 0); \
    acc[M][3] = __builtin_amdgcn_mfma_f32_16x16x32_bf16(AV, FS.bv[3], acc[M][3], 0, 0, 0); \
  } while (0)

  // Tile body: GATE; barrier; stage T+3; read avB (drains under ph1 MFMA);
  // ph1 MFMA on prefetched set; PREFETCH T+1 (drains under ph2); ph2 MFMA.
#define TILEBODY(CUR, NXT, BI, DOSTAGE, GATE, DOPREF) do {            \
    GATE;                                                             \
    __builtin_amdgcn_s_barrier();                                     \
    __builtin_amdgcn_sched_barrier(0);                                \
    if (DOSTAGE) {                                                    \
      u16* Xw  = (u16*)&Xs[((BI)+3)&3][0];                            \
      u16* PAw = (u16*)&PAs[((BI)+3)&3][0];                           \
      gl_lds16(xgp,        Xw + t8);                                  \
      gl_lds16(xgp + half, Xw + 4096 + t8);                           \
      gl_lds16(pgp,        PAw + t8);                                 \
      gl_lds16(pgp + half, PAw + 4096 + t8);                          \
      xgp += 32; pgp += 32;                                           \
    }                                                                 \
    const u16* Xc = &Xs[(BI)][0];                                     \
    bf16x8 w0 = *(const bf16x8*)&Xc[aoff + 2048];                     \
    bf16x8 w1 = *(const bf16x8*)&Xc[aoff + 2560];                     \
    bf16x8 w2 = *(const bf16x8*)&Xc[aoff + 3072];                     \
    bf16x8 w3 = *(const bf16x8*)&Xc[aoff + 3584];                     \
    __builtin_amdgcn_s_setprio(1);                                    \
    MROW4(0, CUR.av[0], CUR); MROW4(1, CUR.av[1], CUR);               \
    MROW4(2, CUR.av[2], CUR); MROW4(3, CUR.av[3], CUR);               \
    __builtin_amdgcn_s_setprio(0);                                    \
    if (DOPREF) PREFETCH(NXT, ((BI)+1)&3);                            \
    __builtin_amdgcn_s_setprio(1);                                    \
    MROW4(4, w0, CUR); MROW4(5, w1, CUR);                             \
    MROW4(6, w2, CUR); MROW4(7, w3, CUR);                             \
    __builtin_amdgcn_s_setprio(0);                                    \
  } while (0)

  // ---- prologue: stage tiles 0,1,2 (12 loads, FIFO per tile)
#pragma unroll
  for (int T = 0; T < 3; ++T) {
    u16* Xw  = (u16*)&Xs[T][0];
    u16* PAw = (u16*)&PAs[T][0];
    gl_lds16(xsrc  + T * 32,        Xw + t8);
    gl_lds16(xsrc  + T * 32 + half, Xw + 4096 + t8);
    gl_lds16(pasrc + T * 32,        PAw + t8);
    gl_lds16(pasrc + T * 32 + half, PAw + 4096 + t8);
  }
  const u16* xgp = xsrc  + 96;   // next staged tile = 3
  const u16* pgp = pasrc + 96;
  GATEV8();                      // tile0's 4 loads landed
  __builtin_amdgcn_s_barrier();
  __builtin_amdgcn_sched_barrier(0);
  PREFETCH(fsA, 0);              // tile0's ph1 fragments

  // ---- main: 28 tiles (stage 3..30), gate vmcnt(4) = "T+1 landed"
  for (int gg = 0; gg < 7; ++gg) {
    TILEBODY(fsA, fsB, 0, 1, GATEV4(), 1);
    TILEBODY(fsB, fsA, 1, 1, GATEV4(), 1);
    TILEBODY(fsA, fsB, 2, 1, GATEV4(), 1);
    TILEBODY(fsB, fsA, 3, 1, GATEV4(), 1);
  }
  // ---- tail: T=28 (stages 31), 29, 30, 31
  TILEBODY(fsA, fsB, 0, 1, GATEV4(), 1);   // T=28
  TILEBODY(fsB, fsA, 1, 0, GATEV4(), 1);   // T=29
  TILEBODY(fsA, fsB, 2, 0, GATEV0(), 1);   // T=30 (T31 fully landed)
  TILEBODY(fsB, fsA, 3, 0, GATENONE(), 0); // T=31 (no prefetch)

#undef TILEBODY
#undef PREFETCH
#undef MROW4

  // ---- epilogue: C/D layout col = lane&15, row = (lane>>4)*4 + j.
  // n even -> px, n odd -> xa, same 16 output cols per (even,odd) pair.
#pragma unroll
  for (int m = 0; m < 8; ++m) {
    const int rl0 = by * 256 + wr * 128 + m * 16 + (lane >> 4) * 4;
    float x2r[4];
#pragma unroll
    for (int j = 0; j < 4; ++j) x2r[j] = x2g[rl0 + j];
#pragma unroll
    for (int g = 0; g < 2; ++g) {
      const int cl = (bx * 8 + wc * 2 + g) * 16 + (lane & 15);
      const float p2c = p2g[cl];
      const float pac = pag[cl];
      const float anc = ang[cl];
      const float Bcc = 1.0f - p2c;
      f32x4 px4 = acc[m][2 * g];
      f32x4 xa4 = acc[m][2 * g + 1];
#pragma unroll
      for (int j = 0; j < 4; ++j) {
        const float px = px4[j];
        const float xa = xa4[j];
        const float Av  = 1.0f - 2.0f * px + x2r[j];
        const float den = fmaxf(1.0f - 2.0f * px + x2r[j] * p2c, EPSF);
        const float dn2 = fmaxf((Av * Av * p2c + Bcc * Bcc * x2r[j] - 2.0f * Av * Bcc * px) / (den * den), EPSF);
        const float sc  = (Bcc * xa - Av * pac) / den;
        const float dv  = fmaxf((1.0f + dn2) * anc, EPSF);
        const float z   = (2.0f * sc) / dv;
        // asinh: |z| <= ~0.13 on this data -> odd poly; exact fallback.
        const float z2 = z * z;
        float r;
        if (z2 > 0.04f) r = asinhf(z);
        else            r = z * (1.0f - z2 * (1.0f / 6.0f) + z2 * z2 * 0.075f);
        out[(size_t)rl0 * Cdim + j * Cdim + cl] = -r;
      }
    }
  }
}

extern "C" void kernel_launch(void* const* d_in, const int* in_sizes, int n_in,
                              void* d_out, int out_size, void* d_ws, size_t ws_size,
                              hipStream_t stream) {
  const float* x = (const float*)d_in[0];
  const float* a = (const float*)d_in[1];
  const float* p = (const float*)d_in[2];
  float* out = (float*)d_out;

  char* ws = (char*)d_ws;
  u16* xb  = (u16*)(ws);                                  // 8 MiB
  u16* pab = (u16*)(ws + (size_t)8 * 1024 * 1024);        // 16 MiB
  float* x2 = (float*)(ws + (size_t)24 * 1024 * 1024);    // stats
  float* p2 = x2 + Bdim;
  float* pa = p2 + Cdim;
  float* an = pa + Cdim;

  prep_x <<<Bdim, 256, 0, stream>>>(x, xb, x2);
  prep_pa<<<Cdim, 256, 0, stream>>>(a, p, pab, p2, pa, an);
  gemm_ep<<<dim3(32, 16), 512, 0, stream>>>(xb, pab, x2, p2, pa, an, out);
}

// Round 12
// 110.931 us; speedup vs baseline: 1.1457x; 1.1457x over previous
//
#include <hip/hip_runtime.h>
#include <hip/hip_bf16.h>
#include <math.h>

// HyperbolicMLR: out[b,c] = -asinh( 2*sc_diff_a / ((1+diff_norm2)*|a_c|) )
// R12: R11's 4-wave/256-thr block (2 blocks/CU for cross-block TLP), with the
// WAR race fixed: ring-3 LDS (72KB), per tile: gate vmcnt(6) -> barrier ->
// STAGE(T+2) -> COMPUTE(T). Barrier always separates last read of a slot
// from its re-write. rcp epilogue kept (race, not rcp, caused R11's failure).

#define EPSF 1e-15f
#define MAXN 0.99999f   // (1 - 1e-5) / sqrt(c), c = 1

constexpr int Bdim = 4096;
constexpr int Ddim = 1024;
constexpr int Cdim = 4096;

typedef __bf16 bf16x8 __attribute__((ext_vector_type(8)));
typedef float  f32x4  __attribute__((ext_vector_type(4)));
typedef unsigned short u16;

__device__ __forceinline__ u16 f2bf(float f) {
  __hip_bfloat16 h = __float2bfloat16(f);   // RNE
  return *reinterpret_cast<const u16*>(&h);
}

__device__ __forceinline__ void gl_lds16(const u16* g, u16* l) {
  __builtin_amdgcn_global_load_lds(
      (const __attribute__((address_space(1))) void*)g,
      (__attribute__((address_space(3))) void*)l, 16, 0, 0);
}

// ---------------- prep kernels ----------------

__global__ __launch_bounds__(256) void prep_x(const float* __restrict__ x,
                                              u16* __restrict__ xb,
                                              float* __restrict__ x2o) {
  const int b = blockIdx.x, t = threadIdx.x;
  float4 v = ((const float4*)(x + (size_t)b * Ddim))[t];
  float s = v.x * v.x + v.y * v.y + v.z * v.z + v.w * v.w;
  __shared__ float red[4];
#pragma unroll
  for (int o = 32; o > 0; o >>= 1) s += __shfl_down(s, o);
  if ((t & 63) == 0) red[t >> 6] = s;
  __syncthreads();
  s = red[0] + red[1] + red[2] + red[3];
  float norm  = sqrtf(s);
  float xn    = fmaxf(norm, EPSF);
  float scale = (xn > MAXN) ? (MAXN / xn) : 1.0f;
  if (t == 0) x2o[b] = s * scale * scale;
  ushort4 o4;
  o4.x = f2bf(v.x * scale); o4.y = f2bf(v.y * scale);
  o4.z = f2bf(v.z * scale); o4.w = f2bf(v.w * scale);
  ((ushort4*)(xb + (size_t)b * Ddim))[t] = o4;
}

// P row c -> PA row ((c>>4)<<5)+(c&15); A row c -> +16 (16-row interleave).
// Stores ani = 1/|a_c| (epilogue multiplies instead of divides).
__global__ __launch_bounds__(256) void prep_pa(const float* __restrict__ a,
                                               const float* __restrict__ p,
                                               u16* __restrict__ pab,
                                               float* __restrict__ p2o,
                                               float* __restrict__ pao,
                                               float* __restrict__ anio) {
  const int c = blockIdx.x, t = threadIdx.x;
  float4 av = ((const float4*)(a + (size_t)c * Ddim))[t];
  float4 pv = ((const float4*)(p + (size_t)c * Ddim))[t];
  float sp2 = pv.x * pv.x + pv.y * pv.y + pv.z * pv.z + pv.w * pv.w;
  float spa = pv.x * av.x + pv.y * av.y + pv.z * av.z + pv.w * av.w;
  float sa2 = av.x * av.x + av.y * av.y + av.z * av.z + av.w * av.w;
  __shared__ float red[12];
#pragma unroll
  for (int o = 32; o > 0; o >>= 1) {
    sp2 += __shfl_down(sp2, o);
    spa += __shfl_down(spa, o);
    sa2 += __shfl_down(sa2, o);
  }
  if ((t & 63) == 0) { int w = t >> 6; red[w] = sp2; red[4 + w] = spa; red[8 + w] = sa2; }
  __syncthreads();
  if (t == 0) {
    p2o[c]  = red[0] + red[1] + red[2] + red[3];
    pao[c]  = red[4] + red[5] + red[6] + red[7];
    anio[c] = 1.0f / sqrtf(red[8] + red[9] + red[10] + red[11]);
  }
  const int prP = ((c >> 4) << 5) + (c & 15);
  ushort4 oa, op;
  oa.x = f2bf(av.x); oa.y = f2bf(av.y); oa.z = f2bf(av.z); oa.w = f2bf(av.w);
  op.x = f2bf(pv.x); op.y = f2bf(pv.y); op.z = f2bf(pv.z); op.w = f2bf(pv.w);
  ((ushort4*)(pab + (size_t)prP * Ddim))[t]        = op;
  ((ushort4*)(pab + (size_t)(prP + 16) * Ddim))[t] = oa;
}

// ---------------- fused GEMM + epilogue ----------------
// Block: 256 thr / 4 waves (2x2). Tile 256 X-rows x 128 PA-rows, BK=32.
// Per wave: out 128x64-PA, acc[8][4]; 12 b128 reads + 32 MFMA per tile.
// LDS: ring-3 x (X 16KB + PA 8KB) = 72 KB -> 2 blocks/CU (144/160 KB).

__global__ __launch_bounds__(256, 2) void gemm_ep(
    const u16* __restrict__ xb, const u16* __restrict__ pab,
    const float* __restrict__ x2g, const float* __restrict__ p2g,
    const float* __restrict__ pag, const float* __restrict__ anig,
    float* __restrict__ out) {
  __shared__ u16 Xs[3][8192];      // [slot][256 rows x 32 u16] = 48 KiB
  __shared__ u16 PAs[3][4096];     // [slot][128 rows x 32 u16] = 24 KiB

  const int t = threadIdx.x;       // 0..255

  // XCD-aware bijective swizzle: 1024 blocks = 8 chunks x 128
  const int flat  = blockIdx.y * 64 + blockIdx.x;
  const int swz   = (flat & 7) * 128 + (flat >> 3);
  const int chunk = swz >> 7;                  // 0..7
  const int local = swz & 127;
  const int by = chunk * 2 + (local >> 6);     // 0..15  X row-group (256 rows)
  const int bx = local & 63;                   // 0..63  PA col-group (128 PA rows)

  const int lane = t & 63;
  const int wid  = t >> 6;       // 0..3
  const int wr   = wid >> 1;     // 0..1  (row half: 128 rows)
  const int wc   = wid & 1;      // 0..1  (PA half: 64 rows)

  // staging: thread t covers (r0 = t>>2, slot = t&3) of a 64-row unit;
  // source k-chunk pre-swizzled (XOR involution, rule 21 both-sides).
  const int r0  = t >> 2;                              // 0..63
  const int sw8 = ((t & 3) ^ ((r0 >> 1) & 3)) * 8;     // u16
  const u16* xsrc  = xb  + (size_t)(by * 256 + r0) * Ddim + sw8;
  const u16* pasrc = pab + (size_t)(bx * 128 + r0) * Ddim + sw8;
  const int t8 = t * 8;
  const size_t q64 = (size_t)64 * Ddim;     // 64-row stride in source

  // fragment read offsets (u16 units): row*32 + swizzled slot*8
  const int arow = wr * 128 + (lane & 15);
  const int brow = wc * 64  + (lane & 15);
  const int aoff = arow * 32 + (((lane >> 4) ^ ((arow >> 1) & 3)) * 8);
  const int boff = brow * 32 + (((lane >> 4) ^ ((brow >> 1) & 3)) * 8);

  f32x4 acc[8][4];
  const f32x4 zero = {0.f, 0.f, 0.f, 0.f};
#pragma unroll
  for (int m = 0; m < 8; ++m)
#pragma unroll
    for (int n = 0; n < 4; ++n) acc[m][n] = zero;

#define STAGE(SLOT) do {                                              \
    u16* Xw  = (u16*)&Xs[(SLOT)][0];                                  \
    u16* PAw = (u16*)&PAs[(SLOT)][0];                                 \
    gl_lds16(xgp,            Xw + t8);                                \
    gl_lds16(xgp + q64,      Xw + 2048 + t8);                         \
    gl_lds16(xgp + 2 * q64,  Xw + 4096 + t8);                         \
    gl_lds16(xgp + 3 * q64,  Xw + 6144 + t8);                         \
    gl_lds16(pgp,            PAw + t8);                               \
    gl_lds16(pgp + q64,      PAw + 2048 + t8);                        \
    xgp += 32; pgp += 32;                                             \
  } while (0)

#define COMPUTE(SLOT) do {                                            \
    const u16* Xr  = &Xs[(SLOT)][0];                                  \
    const u16* PAr = &PAs[(SLOT)][0];                                 \
    bf16x8 bv0 = *(const bf16x8*)&PAr[boff];                          \
    bf16x8 bv1 = *(const bf16x8*)&PAr[boff + 512];                    \
    bf16x8 bv2 = *(const bf16x8*)&PAr[boff + 1024];                   \
    bf16x8 bv3 = *(const bf16x8*)&PAr[boff + 1536];                   \
    bf16x8 a0 = *(const bf16x8*)&Xr[aoff];                            \
    bf16x8 a1 = *(const bf16x8*)&Xr[aoff + 512];                      \
    bf16x8 a2 = *(const bf16x8*)&Xr[aoff + 1024];                     \
    bf16x8 a3 = *(const bf16x8*)&Xr[aoff + 1536];                     \
    bf16x8 a4 = *(const bf16x8*)&Xr[aoff + 2048];                     \
    bf16x8 a5 = *(const bf16x8*)&Xr[aoff + 2560];                     \
    bf16x8 a6 = *(const bf16x8*)&Xr[aoff + 3072];                     \
    bf16x8 a7 = *(const bf16x8*)&Xr[aoff + 3584];                     \
    __builtin_amdgcn_s_setprio(1);                                    \
    _Pragma("unroll")                                                 \
    for (int n = 0; n < 4; ++n) {                                     \
      bf16x8 bv = (n == 0) ? bv0 : (n == 1) ? bv1 : (n == 2) ? bv2 : bv3; \
      acc[0][n] = __builtin_amdgcn_mfma_f32_16x16x32_bf16(a0, bv, acc[0][n], 0, 0, 0); \
      acc[1][n] = __builtin_amdgcn_mfma_f32_16x16x32_bf16(a1, bv, acc[1][n], 0, 0, 0); \
      acc[2][n] = __builtin_amdgcn_mfma_f32_16x16x32_bf16(a2, bv, acc[2][n], 0, 0, 0); \
      acc[3][n] = __builtin_amdgcn_mfma_f32_16x16x32_bf16(a3, bv, acc[3][n], 0, 0, 0); \
      acc[4][n] = __builtin_amdgcn_mfma_f32_16x16x32_bf16(a4, bv, acc[4][n], 0, 0, 0); \
      acc[5][n] = __builtin_amdgcn_mfma_f32_16x16x32_bf16(a5, bv, acc[5][n], 0, 0, 0); \
      acc[6][n] = __builtin_amdgcn_mfma_f32_16x16x32_bf16(a6, bv, acc[6][n], 0, 0, 0); \
      acc[7][n] = __builtin_amdgcn_mfma_f32_16x16x32_bf16(a7, bv, acc[7][n], 0, 0, 0); \
    }                                                                 \
    __builtin_amdgcn_s_setprio(0);                                    \
  } while (0)

#define GATE_BAR(N) do {                                              \
    asm volatile("s_waitcnt vmcnt(" #N ")" ::: "memory");             \
    __builtin_amdgcn_s_barrier();                                     \
    __builtin_amdgcn_sched_barrier(0);                                \
  } while (0)

  // ---- prologue: stage tiles 0 (slot0) and 1 (slot1)
  const u16* xgp = xsrc;
  const u16* pgp = pasrc;
  STAGE(0);
  STAGE(1);

  // ---- main loop: T=0..29 in groups of 3.
  // Per tile: gate vmcnt(6) [tile T landed] -> barrier -> STAGE(T+2, slot
  // (T+2)%3) [slot last read at T-1, before this barrier: WAR-safe] ->
  // COMPUTE(T, slot T%3).
  for (int g = 0; g < 10; ++g) {
    GATE_BAR(6);  STAGE(2);  COMPUTE(0);     // T=3g+0
    GATE_BAR(6);  STAGE(0);  COMPUTE(1);     // T=3g+1
    GATE_BAR(6);  STAGE(1);  COMPUTE(2);     // T=3g+2
  }
  // ---- tail: T=30 (slot0, no stage), T=31 (slot1, no stage)
  GATE_BAR(6);  COMPUTE(0);
  GATE_BAR(0);  COMPUTE(1);

#undef GATE_BAR
#undef STAGE
#undef COMPUTE

  // ---- epilogue: C/D layout col = lane&15, row = (lane>>4)*4 + j.
  // n even -> px, n odd -> xa, same 16 output cols per (even,odd) pair.
  // rcp-based (v_rcp rel err ~6e-5 -> output err ~3e-5, threshold 2.5e-3).
#pragma unroll
  for (int m = 0; m < 8; ++m) {
    const int rl0 = by * 256 + wr * 128 + m * 16 + (lane >> 4) * 4;
    const float4 x2r4 = *(const float4*)&x2g[rl0];
    float x2r[4] = {x2r4.x, x2r4.y, x2r4.z, x2r4.w};
#pragma unroll
    for (int g = 0; g < 2; ++g) {
      const int cl = bx * 64 + wc * 32 + g * 16 + (lane & 15);
      const float p2c = p2g[cl];
      const float pac = pag[cl];
      const float ani = anig[cl];
      const float Bcc = 1.0f - p2c;
      f32x4 px4 = acc[m][2 * g];
      f32x4 xa4 = acc[m][2 * g + 1];
#pragma unroll
      for (int j = 0; j < 4; ++j) {
        const float px = px4[j];
        const float xa = xa4[j];
        const float Av   = 1.0f - 2.0f * px + x2r[j];
        const float den  = fmaxf(1.0f - 2.0f * px + x2r[j] * p2c, EPSF);
        const float rden = __builtin_amdgcn_rcpf(den);
        const float dn2  = fmaxf((Av * Av * p2c + Bcc * Bcc * x2r[j] - 2.0f * Av * Bcc * px) * rden * rden, EPSF);
        const float sc   = (Bcc * xa - Av * pac) * rden;
        const float z    = 2.0f * sc * ani * __builtin_amdgcn_rcpf(1.0f + dn2);
        // asinh: |z| small on this data -> odd poly; exact fallback.
        const float z2 = z * z;
        float r;
        if (z2 > 0.04f) r = asinhf(z);
        else            r = z * (1.0f - z2 * (1.0f / 6.0f) + z2 * z2 * 0.075f);
        out[(size_t)rl0 * Cdim + j * Cdim + cl] = -r;
      }
    }
  }
}

extern "C" void kernel_launch(void* const* d_in, const int* in_sizes, int n_in,
                              void* d_out, int out_size, void* d_ws, size_t ws_size,
                              hipStream_t stream) {
  const float* x = (const float*)d_in[0];
  const float* a = (const float*)d_in[1];
  const float* p = (const float*)d_in[2];
  float* out = (float*)d_out;

  char* ws = (char*)d_ws;
  u16* xb  = (u16*)(ws);                                  // 8 MiB
  u16* pab = (u16*)(ws + (size_t)8 * 1024 * 1024);        // 16 MiB
  float* x2  = (float*)(ws + (size_t)24 * 1024 * 1024);   // stats
  float* p2  = x2 + Bdim;
  float* pa  = p2 + Cdim;
  float* ani = pa + Cdim;

  prep_x <<<Bdim, 256, 0, stream>>>(x, xb, x2);
  prep_pa<<<Cdim, 256, 0, stream>>>(a, p, pab, p2, pa, ani);
  gemm_ep<<<dim3(64, 16), 256, 0, stream>>>(xb, pab, x2, p2, pa, ani, out);
}